// Round 4
// baseline (508.571 us; speedup 1.0000x reference)
//
#include <hip/hip_runtime.h>
#include <hip/hip_bf16.h>

#define B_SZ   8192
#define F_CNT  16
#define E_DIM  32
#define V_CNT  100000
#define D_CNT  8
#define H1     1024
#define H2     512
#define IN_DIM 512
#define EPS_BN 1e-5f

typedef __attribute__((ext_vector_type(8))) unsigned short ushort8;
typedef __attribute__((ext_vector_type(8))) short          frag_ab;
typedef __attribute__((ext_vector_type(4))) float          frag_cd;
typedef __attribute__((ext_vector_type(4))) float          float4v;
typedef __attribute__((ext_vector_type(2))) float          float2v;

__device__ inline unsigned short f2b(float f) {
    unsigned int u = __builtin_bit_cast(unsigned int, f);
    unsigned int r = u + 0x7FFFu + ((u >> 16) & 1u);   // RNE
    return (unsigned short)(r >> 16);
}
__device__ inline float b2f(unsigned short b) {
    return __builtin_bit_cast(float, (unsigned int)b << 16);
}

// async global->LDS DMA, 16B per lane; LDS dest = wave-uniform base + lane*16
__device__ inline void ld_lds16(const unsigned short* g, unsigned short* l) {
    __builtin_amdgcn_global_load_lds(
        (const __attribute__((address_space(1))) unsigned int*)g,
        (__attribute__((address_space(3))) unsigned int*)l, 16, 0, 0);
}

// ---- merged init: W1/W2/W3/b3 fp32->bf16 + zero stats ------------------------
__global__ void k_init(const float* __restrict__ W1, const float* __restrict__ W2,
                       const float* __restrict__ W3, const float* __restrict__ b3,
                       unsigned short* __restrict__ W1c, unsigned short* __restrict__ W2c,
                       unsigned short* __restrict__ W3c, unsigned short* __restrict__ b3c,
                       float* __restrict__ zb) {
    int bid = blockIdx.x, t = threadIdx.x;
    if (bid < 8192) {
        const float* src = (bid < 4096) ? W1 : W2;
        unsigned short* dst = (bid < 4096) ? W1c : W2c;
        long i = ((long)(bid & 4095) * 256 + t) * 4;
        float4v v = *(const float4v*)(src + i);
        dst[i]     = f2b(v[0]);
        dst[i + 1] = f2b(v[1]);
        dst[i + 2] = f2b(v[2]);
        dst[i + 3] = f2b(v[3]);
    } else if (bid == 8192) {
        const float* s = W3 + t * 16;
        unsigned short* d = W3c + t * 16;
#pragma unroll
        for (int j = 0; j < 4; j++) {
            float4v v = *(const float4v*)(s + j * 4);
            d[j * 4 + 0] = f2b(v[0]); d[j * 4 + 1] = f2b(v[1]);
            d[j * 4 + 2] = f2b(v[2]); d[j * 4 + 3] = f2b(v[3]);
        }
        if (t < D_CNT) b3c[t] = f2b(b3[t]);
    } else {
        int i = (bid - 8193) * 1024 + t * 4;
        if (i < 24576) *(float4v*)(zb + i) = (float4v){0.f, 0.f, 0.f, 0.f};
    }
}

// ---- embedding gather fp32 tables -> bf16 emb[b, f*32+e] ---------------------
__global__ void k_gather(const int* __restrict__ feat_ids,
                         const float* __restrict__ tables,
                         unsigned short* __restrict__ emb) {
    int tid = blockIdx.x * 256 + threadIdx.x;    // B*64 threads, 8-elem chunks
    int b = tid >> 6;
    int c = tid & 63;
    int f = c >> 2;
    int id = feat_ids[b * F_CNT + f];
    const float* s = tables + ((long)f * V_CNT + id) * E_DIM + (c & 3) * 8;
    float4v v0 = *(const float4v*)s;
    float4v v1 = *(const float4v*)(s + 4);
    ushort8 o;
#pragma unroll
    for (int i = 0; i < 4; i++) { o[i] = f2b(v0[i]); o[i + 4] = f2b(v1[i]); }
    *(ushort8*)(emb + (long)b * IN_DIM + c * 8) = o;
}

// ---- Layer-1 GEMM: 256x256 tile, BK=64, 8 waves, 2 phases/K-tile -------------
// Round-3 lesson: 4-phase/K-tile had 3 barriers/phase and reloaded bf per
// m-half (32 b128/K-tile). Merged: ONE barrier/phase, af[8]+bf[4] = 24
// b128/K-tile -> LDS-read ~384cy vs MFMA ~310cy per phase, near-balanced.
// vmcnt: 4 DMA/phase, plane staged 2 phases ahead -> boundary vmcnt(4);
// vmcnt(0) only at final half. LDS [buf][plane][256][32] = 128 KiB.
__global__ __launch_bounds__(512, 2)
void k_gemm1(const unsigned short* __restrict__ A,
             const unsigned short* __restrict__ W,
             unsigned short* __restrict__ C,
             float* __restrict__ gsum, float* __restrict__ gsq,
             int M, int N, int K, long aBatchStride, int d0) {
    const int z  = blockIdx.z;
    const int m0 = blockIdx.x * 256;
    const int n0 = blockIdx.y * 256;
    const unsigned short* Ad = A + (long)z * aBatchStride;
    const unsigned short* Wd = W + (long)(d0 + z) * (long)N * K;

    __shared__ unsigned short As[2 * 2 * 8192];   // [buf][plane][256][32] = 64 KiB
    __shared__ unsigned short Bs[2 * 2 * 8192];

    const int t    = threadIdx.x;
    const int w    = t >> 6;
    const int lane = t & 63;
    const int wr   = w >> 2;          // wave row 0..1 (128 rows)
    const int wc   = w & 3;           // wave col 0..3 (64 cols)
    const int q    = lane >> 4;
    const int lr   = lane & 15;
    const int srow = lane >> 2;
    const int scol = (lane & 3) * 8;

    const unsigned short* aG0 = Ad + (long)(m0 + w * 16 + srow) * K + scol;
    const unsigned short* aG1 = aG0 + 128 * (long)K;
    const unsigned short* wG0 = Wd + (long)(n0 + w * 16 + srow) * K + scol;
    const unsigned short* wG1 = wG0 + 128 * (long)K;

    frag_cd acc[8][4];
#pragma unroll
    for (int i = 0; i < 8; i++)
#pragma unroll
        for (int j = 0; j < 4; j++)
            acc[i][j] = (frag_cd){0.f, 0.f, 0.f, 0.f};

    const int NT = K >> 6;

    // prologue: stage tile 0, plane 0 first (oldest 4 = plane 0)
#pragma unroll
    for (int ks = 0; ks < 2; ++ks) {
        ld_lds16(aG0 + ks * 32, &As[ks * 8192 + w * 512]);
        ld_lds16(aG1 + ks * 32, &As[ks * 8192 + 4096 + w * 512]);
        ld_lds16(wG0 + ks * 32, &Bs[ks * 8192 + w * 512]);
        ld_lds16(wG1 + ks * 32, &Bs[ks * 8192 + 4096 + w * 512]);
    }

    for (int tt = 0; tt < NT; ++tt) {
        const int b = tt & 1;
        const bool lastT = (tt == NT - 1);
#pragma unroll
        for (int ks = 0; ks < 2; ++ks) {
            if (lastT && ks == 1)
                asm volatile("s_waitcnt vmcnt(0)" ::: "memory");
            else
                asm volatile("s_waitcnt vmcnt(4)" ::: "memory");
            __builtin_amdgcn_s_barrier();
            if (!lastT) {                       // prefetch tile t+1, plane ks
                const long ko = (long)(tt + 1) * 64 + ks * 32;
                const int  db = (b ^ 1) * 16384 + ks * 8192 + w * 512;
                ld_lds16(aG0 + ko, &As[db]);
                ld_lds16(aG1 + ko, &As[db + 4096]);
                ld_lds16(wG0 + ko, &Bs[db]);
                ld_lds16(wG1 + ko, &Bs[db + 4096]);
            }
            frag_ab af[8], bf[4];
            const unsigned short* Ap = &As[b * 16384 + ks * 8192];
            const unsigned short* Bp = &Bs[b * 16384 + ks * 8192];
#pragma unroll
            for (int i = 0; i < 8; ++i)
                af[i] = *(const frag_ab*)&Ap[(wr * 128 + i * 16 + lr) * 32 + q * 8];
#pragma unroll
            for (int j = 0; j < 4; ++j)
                bf[j] = *(const frag_ab*)&Bp[(wc * 64 + j * 16 + lr) * 32 + q * 8];
            __builtin_amdgcn_s_setprio(1);
#pragma unroll
            for (int i = 0; i < 8; ++i)
#pragma unroll
                for (int j = 0; j < 4; ++j)
                    acc[i][j] = __builtin_amdgcn_mfma_f32_16x16x32_bf16(
                        af[i], bf[j], acc[i][j], 0, 0, 0);
            __builtin_amdgcn_s_setprio(0);
        }
    }

    // epilogue: bf16 C store + per-column sum/sumsq atomics (no fence; R1 lesson)
    unsigned short* Cd = C + (long)z * (long)M * N;
    float s[4], q2[4];
#pragma unroll
    for (int j = 0; j < 4; j++) { s[j] = 0.f; q2[j] = 0.f; }
#pragma unroll
    for (int I = 0; I < 8; ++I) {
        int row = m0 + wr * 128 + I * 16 + q * 4;   // C/D: col=lane&15, row=quad*4+reg
#pragma unroll
        for (int j = 0; j < 4; ++j) {
            int col = n0 + wc * 64 + j * 16 + lr;
#pragma unroll
            for (int r = 0; r < 4; ++r) {
                float v = acc[I][j][r];
                Cd[(long)(row + r) * N + col] = f2b(v);
                s[j] += v; q2[j] += v * v;
            }
        }
    }
#pragma unroll
    for (int j = 0; j < 4; j++) {
        s[j]  += __shfl_xor(s[j], 16, 64);  s[j]  += __shfl_xor(s[j], 32, 64);
        q2[j] += __shfl_xor(q2[j], 16, 64); q2[j] += __shfl_xor(q2[j], 32, 64);
    }
    if (lane < 16) {
        float* gs = gsum + (long)(d0 + z) * N + n0 + wc * 64;
        float* gq = gsq  + (long)(d0 + z) * N + n0 + wc * 64;
#pragma unroll
        for (int j = 0; j < 4; j++) {
            atomicAdd(&gs[j * 16 + lane], s[j]);
            atomicAdd(&gq[j * 16 + lane], q2[j]);
        }
    }
}

// ---- Layer-2 GEMM: 256x256 tile, same schedule; A reg-staged with fused ------
// BN1(scale/shift from LDS)+ReLU, W via DMA. A pipeline: load pair at phase g
// (after this phase's 2 W-DMAs; 4 vmem/phase), transform+ds_write at phase g+1
// (wait vmcnt(4) = the 4 ops issued at g+1), read at g+2. sc/sh staged in LDS
// once so transform reads are lgkm, not vmcnt. Masked h2 store: only rows with
// domain_id[row]==d are ever read downstream; stats come from accumulators.
__global__ __launch_bounds__(512, 2)
void k_gemm2(const unsigned short* __restrict__ A,
             const unsigned short* __restrict__ W,
             unsigned short* __restrict__ C,
             float* __restrict__ gsum, float* __restrict__ gsq,
             const float* __restrict__ sc1, const float* __restrict__ sh1,
             const int* __restrict__ dom,
             int M, int N, int K, long aBatchStride, int d0) {
    const int z    = blockIdx.z;
    const int m0   = blockIdx.x * 256;
    const int n0   = blockIdx.y * 256;
    const int dcur = d0 + z;
    const unsigned short* Ad = A + (long)z * aBatchStride;
    const unsigned short* Wd = W + (long)dcur * (long)N * K;

    __shared__ unsigned short As[2 * 2 * 8192];
    __shared__ unsigned short Bs[2 * 2 * 8192];
    __shared__ float scLds[1024];
    __shared__ float shLds[1024];

    const int t    = threadIdx.x;
    const int w    = t >> 6;
    const int lane = t & 63;
    const int wr   = w >> 2;
    const int wc   = w & 3;
    const int q    = lane >> 4;
    const int lr   = lane & 15;
    const int srow = lane >> 2;
    const int scol = (lane & 3) * 8;

    const unsigned short* aG0 = Ad + (long)(m0 + w * 16 + srow) * K + scol;
    const unsigned short* aG1 = aG0 + 128 * (long)K;
    const unsigned short* wG0 = Wd + (long)(n0 + w * 16 + srow) * K + scol;
    const unsigned short* wG1 = wG0 + 128 * (long)K;
    const float* scD = sc1 + (long)dcur * K;
    const float* shD = sh1 + (long)dcur * K;

    frag_cd acc[8][4];
#pragma unroll
    for (int i = 0; i < 8; i++)
#pragma unroll
        for (int j = 0; j < 4; j++)
            acc[i][j] = (frag_cd){0.f, 0.f, 0.f, 0.f};

    const int NT = K >> 6;   // 16

    // ---- prologue: W DMA (planes 0,1) + A loads to regs + sc/sh prefill ------
    ld_lds16(wG0,      &Bs[w * 512]);
    ld_lds16(wG1,      &Bs[4096 + w * 512]);
    ld_lds16(wG0 + 32, &Bs[8192 + w * 512]);
    ld_lds16(wG1 + 32, &Bs[8192 + 4096 + w * 512]);
    ushort8 p00 = *(const ushort8*)aG0;
    ushort8 p01 = *(const ushort8*)aG1;
    ushort8 p10 = *(const ushort8*)(aG0 + 32);
    ushort8 p11 = *(const ushort8*)(aG1 + 32);
    *(float2v*)&scLds[t * 2] = *(const float2v*)&scD[t * 2];
    *(float2v*)&shLds[t * 2] = *(const float2v*)&shD[t * 2];
    __syncthreads();   // drains vmcnt+lgkm; scLds visible

    // transform tile 0 (planes 0,1) into buf 0
#pragma unroll
    for (int ks = 0; ks < 2; ++ks) {
        const int kp = ks * 32 + scol;
        float4v sa = *(const float4v*)&scLds[kp];
        float4v sb = *(const float4v*)&scLds[kp + 4];
        float4v ha = *(const float4v*)&shLds[kp];
        float4v hb = *(const float4v*)&shLds[kp + 4];
        ushort8 x0 = ks ? p10 : p00;
        ushort8 x1 = ks ? p11 : p01;
        ushort8 y0, y1;
#pragma unroll
        for (int i2 = 0; i2 < 8; i2++) {
            float scv = (i2 < 4) ? sa[i2] : sb[i2 - 4];
            float shv = (i2 < 4) ? ha[i2] : hb[i2 - 4];
            y0[i2] = f2b(fmaxf(b2f(x0[i2]) * scv + shv, 0.f));
            y1[i2] = f2b(fmaxf(b2f(x1[i2]) * scv + shv, 0.f));
        }
        *(ushort8*)&As[ks * 8192 + w * 512 + lane * 8] = y0;
        *(ushort8*)&As[ks * 8192 + 4096 + w * 512 + lane * 8] = y1;
    }
    __syncthreads();   // tile-0 A visible

    ushort8 xp0, xp1;
    int pOff = 0;

    for (int tt = 0; tt < NT; ++tt) {
        const int b = tt & 1;
        const bool lastT = (tt == NT - 1);
#pragma unroll
        for (int ks = 0; ks < 2; ++ks) {
            if (lastT && ks == 1)
                asm volatile("s_waitcnt vmcnt(0)" ::: "memory");
            else
                asm volatile("s_waitcnt vmcnt(4)" ::: "memory");
            __builtin_amdgcn_s_barrier();

            ushort8 xn0, xn1; int nOff;
            if (!lastT) {                       // issue W DMA + A reg-loads (4 vmem)
                const long ko = (long)(tt + 1) * 64 + ks * 32;
                const int  db = ((tt + 1) & 1) * 16384 + ks * 8192 + w * 512;
                ld_lds16(wG0 + ko, &Bs[db]);
                ld_lds16(wG1 + ko, &Bs[db + 4096]);
                xn0 = *(const ushort8*)(aG0 + ko);
                xn1 = *(const ushort8*)(aG1 + ko);
                nOff = db;
            } else { xn0 = xp0; xn1 = xp1; nOff = pOff; }

            // transform+write pair loaded last phase (lands 1 phase before read)
            const bool pend = ks ? (tt < NT - 1) : (tt > 0);
            if (pend) {
                if (!lastT) asm volatile("s_waitcnt vmcnt(4)" ::: "memory");
                else        asm volatile("s_waitcnt vmcnt(0)" ::: "memory");
                const int kp = tt * 64 + 32 + ks * 32 + scol;
                float4v sa = *(const float4v*)&scLds[kp];
                float4v sb = *(const float4v*)&scLds[kp + 4];
                float4v ha = *(const float4v*)&shLds[kp];
                float4v hb = *(const float4v*)&shLds[kp + 4];
                ushort8 y0, y1;
#pragma unroll
                for (int i2 = 0; i2 < 8; i2++) {
                    float scv = (i2 < 4) ? sa[i2] : sb[i2 - 4];
                    float shv = (i2 < 4) ? ha[i2] : hb[i2 - 4];
                    y0[i2] = f2b(fmaxf(b2f(xp0[i2]) * scv + shv, 0.f));
                    y1[i2] = f2b(fmaxf(b2f(xp1[i2]) * scv + shv, 0.f));
                }
                *(ushort8*)&As[pOff + lane * 8] = y0;
                *(ushort8*)&As[pOff + 4096 + lane * 8] = y1;
            }
            xp0 = xn0; xp1 = xn1; pOff = nOff;

            frag_ab af[8], bf[4];
            const unsigned short* Ap = &As[b * 16384 + ks * 8192];
            const unsigned short* Bp = &Bs[b * 16384 + ks * 8192];
#pragma unroll
            for (int i = 0; i < 8; ++i)
                af[i] = *(const frag_ab*)&Ap[(wr * 128 + i * 16 + lr) * 32 + q * 8];
#pragma unroll
            for (int j = 0; j < 4; ++j)
                bf[j] = *(const frag_ab*)&Bp[(wc * 64 + j * 16 + lr) * 32 + q * 8];
            asm volatile("s_waitcnt lgkmcnt(0)" ::: "memory");   // drain ds_writes too
            __builtin_amdgcn_sched_barrier(0);                   // rule 18
            __builtin_amdgcn_s_setprio(1);
#pragma unroll
            for (int i = 0; i < 8; ++i)
#pragma unroll
                for (int j = 0; j < 4; ++j)
                    acc[i][j] = __builtin_amdgcn_mfma_f32_16x16x32_bf16(
                        af[i], bf[j], acc[i][j], 0, 0, 0);
            __builtin_amdgcn_s_setprio(0);
        }
    }

    // epilogue: masked bf16 store (only domain-matching rows) + full stats
    unsigned short* Cd = C + (long)z * (long)M * N;
    float s[4], q2[4];
#pragma unroll
    for (int j = 0; j < 4; j++) { s[j] = 0.f; q2[j] = 0.f; }
#pragma unroll
    for (int I = 0; I < 8; ++I) {
        int row = m0 + wr * 128 + I * 16 + q * 4;
        int dm[4];
#pragma unroll
        for (int r = 0; r < 4; ++r) dm[r] = dom[row + r];
#pragma unroll
        for (int j = 0; j < 4; ++j) {
            int col = n0 + wc * 64 + j * 16 + lr;
#pragma unroll
            for (int r = 0; r < 4; ++r) {
                float v = acc[I][j][r];
                s[j] += v; q2[j] += v * v;
                if (dm[r] == dcur)
                    Cd[(long)(row + r) * N + col] = f2b(v);
            }
        }
    }
#pragma unroll
    for (int j = 0; j < 4; j++) {
        s[j]  += __shfl_xor(s[j], 16, 64);  s[j]  += __shfl_xor(s[j], 32, 64);
        q2[j] += __shfl_xor(q2[j], 16, 64); q2[j] += __shfl_xor(q2[j], 32, 64);
    }
    if (lane < 16) {
        float* gs = gsum + (long)dcur * N + n0 + wc * 64;
        float* gq = gsq  + (long)dcur * N + n0 + wc * 64;
#pragma unroll
        for (int j = 0; j < 4; j++) {
            atomicAdd(&gs[j * 16 + lane], s[j]);
            atomicAdd(&gq[j * 16 + lane], q2[j]);
        }
    }
}

// ---- stats -> scale/shift (fp32 g/be) ----------------------------------------
__global__ void k_finalize(const float* __restrict__ gsum, const float* __restrict__ gsq,
                           const float* __restrict__ g, const float* __restrict__ be,
                           float* __restrict__ scale, float* __restrict__ shift, int n,
                           int gOff) {
    int i = blockIdx.x * 256 + threadIdx.x;
    if (i >= n) return;
    float mean = gsum[i] * (1.0f / B_SZ);
    float var  = gsq[i] * (1.0f / B_SZ) - mean * mean;
    float sc   = g[gOff + i] * rsqrtf(var + EPS_BN);
    scale[i] = sc;
    shift[i] = be[gOff + i] - mean * sc;
}

// ---- fused BN2+ReLU+W3 dot+sigmoid+domain select (fp32 out) -------------------
__global__ void k_final(const unsigned short* __restrict__ h2c,
                        const int* __restrict__ domain_id,
                        const float* __restrict__ scale2, const float* __restrict__ shift2,
                        const unsigned short* __restrict__ W3, const unsigned short* __restrict__ b3,
                        float* __restrict__ out, int d0, int nc) {
    int wave = threadIdx.x >> 6, lane = threadIdx.x & 63;
    int b = blockIdx.x * 4 + wave;
    int d = domain_id[b];
    if (d < d0 || d >= d0 + nc) return;
    int o = d * H2 + lane * 8;
    ushort8 v = *(const ushort8*)(h2c + ((long)(d - d0) * B_SZ + b) * H2 + lane * 8);
    ushort8 w = *(const ushort8*)(W3 + o);
    float sum = 0.f;
#pragma unroll
    for (int i = 0; i < 8; i++) {
        float x = b2f(v[i]) * scale2[o + i] + shift2[o + i];
        sum += fmaxf(x, 0.f) * b2f(w[i]);
    }
#pragma unroll
    for (int off = 32; off > 0; off >>= 1) sum += __shfl_xor(sum, off, 64);
    if (lane == 0)
        out[b] = 1.f / (1.f + expf(-(sum + b2f(b3[d]))));
}

__global__ void k_sentinel(float* __restrict__ out, int n) {
    int i = blockIdx.x * 256 + threadIdx.x;
    if (i < n) out[i] = 0.25f;
}

extern "C" void kernel_launch(void* const* d_in, const int* in_sizes, int n_in,
                              void* d_out, int out_size, void* d_ws, size_t ws_size,
                              hipStream_t stream) {
    const int*   feat_ids  = (const int*)d_in[0];
    const int*   domain_id = (const int*)d_in[1];
    const float* tables = (const float*)d_in[2];
    const float* W1  = (const float*)d_in[3];
    const float* g1  = (const float*)d_in[5];
    const float* be1 = (const float*)d_in[6];
    const float* W2  = (const float*)d_in[7];
    const float* g2  = (const float*)d_in[9];
    const float* be2 = (const float*)d_in[10];
    const float* W3  = (const float*)d_in[11];
    const float* b3  = (const float*)d_in[12];

    char* ws = (char*)d_ws;
    float* gsum1  = (float*)ws;            // 8192
    float* gsq1   = gsum1 + 8192;          // 8192
    float* gsum2  = gsq1 + 8192;           // 4096
    float* gsq2   = gsum2 + 4096;          // 4096
    float* scale1 = gsq2 + 4096;           // 8192 (absolute [D][H1])
    float* shift1 = scale1 + 8192;         // 8192
    float* scale2 = shift1 + 8192;         // 4096 (absolute [D][H2])
    float* shift2 = scale2 + 4096;         // 4096
    unsigned short* W1c = (unsigned short*)(ws + (1L  << 20));
    unsigned short* W2c = (unsigned short*)(ws + (9L  << 20));
    unsigned short* W3c = (unsigned short*)(ws + (17L << 20));
    unsigned short* b3c = W3c + D_CNT * H2;
    unsigned short* emb = (unsigned short*)(ws + (18L << 20));

    const long h1Elems = (long)B_SZ * H1;
    const long h2Elems = (long)B_SZ * H2;
    const long perDom  = (h1Elems + h2Elems) * 2;
    const long baseOff = 26L << 20;
    int NC = 0;
    for (int cand = 8; cand >= 1; cand >>= 1)
        if (baseOff + (long)cand * perDom <= (long)ws_size) { NC = cand; break; }
    if (NC == 0) {
        k_sentinel<<<dim3((out_size + 255) / 256), dim3(256), 0, stream>>>(
            (float*)d_out, out_size);
        return;
    }
    unsigned short* h1c = (unsigned short*)(ws + baseOff);
    unsigned short* h2c = h1c + (long)NC * h1Elems;

    k_init<<<dim3(8217), dim3(256), 0, stream>>>(W1, W2, W3, b3, W1c, W2c, W3c, b3c, gsum1);
    k_gather<<<dim3(2048), dim3(256), 0, stream>>>(feat_ids, tables, emb);

    for (int d0 = 0; d0 < D_CNT; d0 += NC) {
        // Layer 1: M=8192,N=1024,K=512 ; 256x256 2-phase pipelined tile
        k_gemm1<<<dim3(32, 4, NC), dim3(512), 0, stream>>>(
            emb, W1c, h1c, gsum1, gsq1, 8192, 1024, 512, 0L, d0);
        k_finalize<<<dim3(NC * 4), dim3(256), 0, stream>>>(
            gsum1 + d0 * H1, gsq1 + d0 * H1, g1, be1,
            scale1 + d0 * H1, shift1 + d0 * H1, NC * H1, d0 * H1);
        // Layer 2: M=8192,N=512,K=1024 ; 256x256 tile, fused BN1+ReLU A-staging,
        // masked h2 store
        k_gemm2<<<dim3(32, 2, NC), dim3(512), 0, stream>>>(
            h1c, W2c, h2c, gsum2, gsq2, scale1, shift1, domain_id,
            8192, 512, 1024, h1Elems, d0);
        k_finalize<<<dim3(NC * 2), dim3(256), 0, stream>>>(
            gsum2 + d0 * H2, gsq2 + d0 * H2, g2, be2,
            scale2 + d0 * H2, shift2 + d0 * H2, NC * H2, d0 * H2);
        k_final<<<dim3(2048), dim3(256), 0, stream>>>(
            h2c, domain_id, scale2, shift2, W3c, b3c, (float*)d_out, d0, NC);
    }
}

// Round 5
// 479.876 us; speedup vs baseline: 1.0598x; 1.0598x over previous
//
#include <hip/hip_runtime.h>
#include <hip/hip_bf16.h>

#define B_SZ   8192
#define F_CNT  16
#define E_DIM  32
#define V_CNT  100000
#define D_CNT  8
#define H1     1024
#define H2     512
#define IN_DIM 512
#define EPS_BN 1e-5f

typedef __attribute__((ext_vector_type(8))) unsigned short ushort8;
typedef __attribute__((ext_vector_type(8))) short          frag_ab;
typedef __attribute__((ext_vector_type(4))) float          frag_cd;
typedef __attribute__((ext_vector_type(4))) float          float4v;

__device__ inline unsigned short f2b(float f) {
    unsigned int u = __builtin_bit_cast(unsigned int, f);
    unsigned int r = u + 0x7FFFu + ((u >> 16) & 1u);   // RNE
    return (unsigned short)(r >> 16);
}
__device__ inline float b2f(unsigned short b) {
    return __builtin_bit_cast(float, (unsigned int)b << 16);
}

// async global->LDS DMA, 16B per lane; LDS dest = wave-uniform base + lane*16
__device__ inline void ld_lds16(const unsigned short* g, unsigned short* l) {
    __builtin_amdgcn_global_load_lds(
        (const __attribute__((address_space(1))) unsigned int*)g,
        (__attribute__((address_space(3))) unsigned int*)l, 16, 0, 0);
}

// ---- merged init: W1/W2/W3/b3 fp32->bf16 + zero stats ------------------------
__global__ void k_init(const float* __restrict__ W1, const float* __restrict__ W2,
                       const float* __restrict__ W3, const float* __restrict__ b3,
                       unsigned short* __restrict__ W1c, unsigned short* __restrict__ W2c,
                       unsigned short* __restrict__ W3c, unsigned short* __restrict__ b3c,
                       float* __restrict__ zb) {
    int bid = blockIdx.x, t = threadIdx.x;
    if (bid < 8192) {
        const float* src = (bid < 4096) ? W1 : W2;
        unsigned short* dst = (bid < 4096) ? W1c : W2c;
        long i = ((long)(bid & 4095) * 256 + t) * 4;
        float4v v = *(const float4v*)(src + i);
        dst[i]     = f2b(v[0]);
        dst[i + 1] = f2b(v[1]);
        dst[i + 2] = f2b(v[2]);
        dst[i + 3] = f2b(v[3]);
    } else if (bid == 8192) {
        const float* s = W3 + t * 16;
        unsigned short* d = W3c + t * 16;
#pragma unroll
        for (int j = 0; j < 4; j++) {
            float4v v = *(const float4v*)(s + j * 4);
            d[j * 4 + 0] = f2b(v[0]); d[j * 4 + 1] = f2b(v[1]);
            d[j * 4 + 2] = f2b(v[2]); d[j * 4 + 3] = f2b(v[3]);
        }
        if (t < D_CNT) b3c[t] = f2b(b3[t]);
    } else {
        int i = (bid - 8193) * 1024 + t * 4;
        if (i < 24576) *(float4v*)(zb + i) = (float4v){0.f, 0.f, 0.f, 0.f};
    }
}

// ---- embedding gather fp32 tables -> bf16 emb[b, f*32+e] ---------------------
__global__ void k_gather(const int* __restrict__ feat_ids,
                         const float* __restrict__ tables,
                         unsigned short* __restrict__ emb) {
    int tid = blockIdx.x * 256 + threadIdx.x;    // B*64 threads, 8-elem chunks
    int b = tid >> 6;
    int c = tid & 63;
    int f = c >> 2;
    int id = feat_ids[b * F_CNT + f];
    const float* s = tables + ((long)f * V_CNT + id) * E_DIM + (c & 3) * 8;
    float4v v0 = *(const float4v*)s;
    float4v v1 = *(const float4v*)(s + 4);
    ushort8 o;
#pragma unroll
    for (int i = 0; i < 4; i++) { o[i] = f2b(v0[i]); o[i + 4] = f2b(v1[i]); }
    *(ushort8*)(emb + (long)b * IN_DIM + c * 8) = o;
}

// ---- Layer-1 GEMM: 256x256 tile, BK=64, 8 waves, counted-vmcnt pipeline ------
// Round-3 config (best measured ~112us). Round-4 lesson: merging to 2 coarse
// phases REGRESSED (+13us) — finer phases interleave better across the 2
// waves/SIMD. Keeping the 4-phase schedule verbatim.
__global__ __launch_bounds__(512, 2)
void k_gemm1(const unsigned short* __restrict__ A,
             const unsigned short* __restrict__ W,
             unsigned short* __restrict__ C,
             float* __restrict__ gsum, float* __restrict__ gsq,
             int M, int N, int K, long aBatchStride, int d0) {
    const int z  = blockIdx.z;
    const int m0 = blockIdx.x * 256;
    const int n0 = blockIdx.y * 256;
    const unsigned short* Ad = A + (long)z * aBatchStride;
    const unsigned short* Wd = W + (long)(d0 + z) * (long)N * K;

    __shared__ unsigned short As[2 * 2 * 8192];   // [buf][kh][256][32] bf16 = 64 KiB
    __shared__ unsigned short Bs[2 * 2 * 8192];   // 64 KiB

    const int t    = threadIdx.x;
    const int w    = t >> 6;          // wave 0..7
    const int lane = t & 63;
    const int wr   = w >> 2;          // wave row 0..1 (128 rows each)
    const int wc   = w & 3;           // wave col 0..3 (64 cols each)
    const int q    = lane >> 4;
    const int lr   = lane & 15;

    const int srow = lane >> 2;
    const int scol = (lane & 3) * 8;
    const unsigned short* aGb[2];
    const unsigned short* wGb[2];
    aGb[0] = Ad + (long)(m0 + w * 16 + srow) * K + scol;
    aGb[1] = aGb[0] + (long)128 * K;
    wGb[0] = Wd + (long)(n0 + w * 16 + srow) * K + scol;
    wGb[1] = wGb[0] + (long)128 * K;

    frag_cd acc[8][4];
#pragma unroll
    for (int i = 0; i < 8; i++)
#pragma unroll
        for (int j = 0; j < 4; j++)
            acc[i][j] = (frag_cd){0.f, 0.f, 0.f, 0.f};

    const int NT = K >> 6;            // K-tiles of 64

    // prologue: stage tile 0 into buf0, H0 first (oldest-4 = H0)
#pragma unroll
    for (int p = 0; p < 4; ++p) {
        const int kh = p >> 1, sg = p & 1;
        ld_lds16(aGb[sg] + kh * 32, &As[kh * 8192 + sg * 4096 + w * 512]);
        ld_lds16(wGb[sg] + kh * 32, &Bs[kh * 8192 + sg * 4096 + w * 512]);
    }

    for (int tt = 0; tt < NT; ++tt) {
        const int b = tt & 1;
        const bool lastT = (tt == NT - 1);
#pragma unroll
        for (int p = 0; p < 4; ++p) {
            const int ks = p >> 1;    // k-slice / LDS plane read this phase
            const int mh = p & 1;     // m-half quadrant + staging slot group
            if (p == 0 || p == 2) {   // half boundary: oldest loads = this plane
                if (p == 2 && lastT)
                    asm volatile("s_waitcnt vmcnt(0)" ::: "memory");
                else
                    asm volatile("s_waitcnt vmcnt(4)" ::: "memory");
                __builtin_amdgcn_s_barrier();
            }
            // register subtile ds-loads (compiler inserts fine-grained lgkm waits)
            frag_ab af[4], bf[4];
            const unsigned short* Ap = &As[b * 16384 + ks * 8192];
            const unsigned short* Bp = &Bs[b * 16384 + ks * 8192];
#pragma unroll
            for (int i = 0; i < 4; ++i) {
                af[i] = *(const frag_ab*)&Ap[(wr * 128 + (mh * 4 + i) * 16 + lr) * 32 + q * 8];
                bf[i] = *(const frag_ab*)&Bp[(wc * 64 + i * 16 + lr) * 32 + q * 8];
            }
            // prefetch tile t+1 (half kh=ks, slot group mh) into buf b^1
            if (!lastT) {
                const long ko = (long)(tt + 1) * 64 + ks * 32;
                ld_lds16(aGb[mh] + ko, &As[(b ^ 1) * 16384 + ks * 8192 + mh * 4096 + w * 512]);
                ld_lds16(wGb[mh] + ko, &Bs[(b ^ 1) * 16384 + ks * 8192 + mh * 4096 + w * 512]);
            }
            __builtin_amdgcn_s_barrier();
            asm volatile("s_waitcnt lgkmcnt(0)" ::: "memory");
            __builtin_amdgcn_sched_barrier(0);   // rule 18: pin MFMA after the wait
            __builtin_amdgcn_s_setprio(1);
#pragma unroll
            for (int i = 0; i < 4; ++i)
#pragma unroll
                for (int j = 0; j < 4; ++j)
                    acc[mh * 4 + i][j] = __builtin_amdgcn_mfma_f32_16x16x32_bf16(
                        af[i], bf[j], acc[mh * 4 + i][j], 0, 0, 0);
            __builtin_amdgcn_s_setprio(0);
            __builtin_amdgcn_s_barrier();
        }
    }

    // epilogue: bf16 C store + per-column sum/sumsq atomics (no fence; R1 lesson)
    unsigned short* Cd = C + (long)z * (long)M * N;
    float s[4], q2[4];
#pragma unroll
    for (int j = 0; j < 4; j++) { s[j] = 0.f; q2[j] = 0.f; }
#pragma unroll
    for (int I = 0; I < 8; ++I) {
        int row = m0 + wr * 128 + I * 16 + q * 4;   // C/D: col=lane&15, row=quad*4+reg
#pragma unroll
        for (int j = 0; j < 4; ++j) {
            int col = n0 + wc * 64 + j * 16 + lr;
#pragma unroll
            for (int r = 0; r < 4; ++r) {
                float v = acc[I][j][r];
                Cd[(long)(row + r) * N + col] = f2b(v);
                s[j] += v; q2[j] += v * v;
            }
        }
    }
#pragma unroll
    for (int j = 0; j < 4; j++) {
        s[j]  += __shfl_xor(s[j], 16, 64);  s[j]  += __shfl_xor(s[j], 32, 64);
        q2[j] += __shfl_xor(q2[j], 16, 64); q2[j] += __shfl_xor(q2[j], 32, 64);
    }
    if (lane < 16) {
        float* gs = gsum + (long)(d0 + z) * N + n0 + wc * 64;
        float* gq = gsq  + (long)(d0 + z) * N + n0 + wc * 64;
#pragma unroll
        for (int j = 0; j < 4; j++) {
            atomicAdd(&gs[j * 16 + lane], s[j]);
            atomicAdd(&gq[j * 16 + lane], q2[j]);
        }
    }
}

// ---- Layer-2 GEMM: 128M x 512N (FULL N) tile, 8 waves, m97-style 2-barrier ---
// Round-4 lessons applied by reverting to the round-2 loop structure; the ONE
// change vs round-2/3 is tile width: A (h1c) re-read factor 4 -> 1, so the
// fused BN1+ReLU transform is computed once per element (VALUBusy was 47%).
// Per wave per K-step: af[4] x bf[8] -> 32 MFMA vs 12 ds_read_b128.
// LDS = 40KB -> 2 blocks/CU (grid 64x8 = 2/CU exactly). Unmasked store
// (round-4: masked store inflated WRITE via RFO — reverted).
__global__ __launch_bounds__(512, 2)
void k_gemm2(const unsigned short* __restrict__ A,
             const unsigned short* __restrict__ W,
             unsigned short* __restrict__ C,
             float* __restrict__ gsum, float* __restrict__ gsq,
             const float* __restrict__ sc1, const float* __restrict__ sh1,
             int M, int N, int K, long aBatchStride, int d0) {
    const int z    = blockIdx.z;
    const int m0   = blockIdx.x * 128;
    const int dcur = d0 + z;
    const unsigned short* Ad = A + (long)z * aBatchStride;
    const unsigned short* Wd = W + (long)dcur * (long)N * K;

    __shared__ unsigned short As[128 * 32];   // 8 KB
    __shared__ unsigned short Bs[512 * 32];   // 32 KB

    const int t    = threadIdx.x;
    const int w    = t >> 6;          // 0..7
    const int lane = t & 63;
    const int wm   = (w & 1) << 6;    // 0 / 64
    const int wn   = (w >> 1) << 7;   // 0 / 128 / 256 / 384
    const int q    = lane >> 4;
    const int lr   = lane & 15;
    const int srow = lane >> 2;
    const int scol = (lane & 3) * 8;

    // A reg-staged (BN1+ReLU en route): wave w owns rows [w*16, w*16+16)
    const unsigned short* aP = Ad + (long)(m0 + w * 16 + srow) * K + scol;
    unsigned short* aLw = &As[(w * 16 + srow) * 32 + scol];
    const float* scD = sc1 + (long)dcur * K;
    const float* shD = sh1 + (long)dcur * K;
    // B via DMA: wave w stages rows [w*64, w*64+64) = 4 issues of 16 rows
    const unsigned short* wG[4];
    unsigned short* wL[4];
#pragma unroll
    for (int i = 0; i < 4; ++i) {
        wG[i] = Wd + (long)(w * 64 + i * 16 + srow) * K + scol;
        wL[i] = &Bs[(w * 64 + i * 16) * 32];
    }

    frag_cd acc[4][8];
#pragma unroll
    for (int i = 0; i < 4; i++)
#pragma unroll
        for (int j = 0; j < 8; j++)
            acc[i][j] = (frag_cd){0.f, 0.f, 0.f, 0.f};

    ushort8 x0 = *(const ushort8*)aP;          // prologue A load (k0 = 0)

    for (int k0 = 0; k0 < K; k0 += 32) {
#pragma unroll
        for (int i = 0; i < 4; ++i)
            ld_lds16(wG[i] + k0, wL[i]);       // W DMA in flight over transform
        float4v sa = *(const float4v*)(scD + k0 + scol);
        float4v sb = *(const float4v*)(scD + k0 + scol + 4);
        float4v ha = *(const float4v*)(shD + k0 + scol);
        float4v hb = *(const float4v*)(shD + k0 + scol + 4);
        ushort8 y0;
#pragma unroll
        for (int i2 = 0; i2 < 8; i2++) {
            float scv = (i2 < 4) ? sa[i2] : sb[i2 - 4];
            float shv = (i2 < 4) ? ha[i2] : hb[i2 - 4];
            y0[i2] = f2b(fmaxf(b2f(x0[i2]) * scv + shv, 0.f));
        }
        *(ushort8*)aLw = y0;
        __syncthreads();                       // ds_write visible + W DMA drained

        if (k0 + 32 < K)                       // early-issue next A chunk
            x0 = *(const ushort8*)(aP + k0 + 32);

        frag_ab af[4], bf[8];
#pragma unroll
        for (int i = 0; i < 4; i++)
            af[i] = *(const frag_ab*)&As[(wm + i * 16 + lr) * 32 + q * 8];
#pragma unroll
        for (int j = 0; j < 8; j++)
            bf[j] = *(const frag_ab*)&Bs[(wn + j * 16 + lr) * 32 + q * 8];
#pragma unroll
        for (int i = 0; i < 4; i++)
#pragma unroll
            for (int j = 0; j < 8; j++)
                acc[i][j] = __builtin_amdgcn_mfma_f32_16x16x32_bf16(af[i], bf[j], acc[i][j], 0, 0, 0);
        __syncthreads();
    }

    // epilogue: bf16 C store + per-column sum/sumsq atomics
    unsigned short* Cd = C + (long)z * (long)M * N;
    float s[8], q2[8];
#pragma unroll
    for (int j = 0; j < 8; j++) { s[j] = 0.f; q2[j] = 0.f; }
#pragma unroll
    for (int i = 0; i < 4; i++) {
        int row = m0 + wm + i * 16 + q * 4;
#pragma unroll
        for (int j = 0; j < 8; j++) {
            int col = wn + j * 16 + lr;
#pragma unroll
            for (int r = 0; r < 4; r++) {
                float v = acc[i][j][r];
                Cd[(long)(row + r) * N + col] = f2b(v);
                s[j] += v; q2[j] += v * v;
            }
        }
    }
#pragma unroll
    for (int j = 0; j < 8; j++) {
        s[j]  += __shfl_xor(s[j], 16, 64);  s[j]  += __shfl_xor(s[j], 32, 64);
        q2[j] += __shfl_xor(q2[j], 16, 64); q2[j] += __shfl_xor(q2[j], 32, 64);
    }
    if (lane < 16) {
        float* gs = gsum + (long)dcur * N + wn;
        float* gq = gsq  + (long)dcur * N + wn;
#pragma unroll
        for (int j = 0; j < 8; j++) {
            atomicAdd(&gs[j * 16 + lane], s[j]);
            atomicAdd(&gq[j * 16 + lane], q2[j]);
        }
    }
}

// ---- stats -> scale/shift (fp32 g/be) ----------------------------------------
__global__ void k_finalize(const float* __restrict__ gsum, const float* __restrict__ gsq,
                           const float* __restrict__ g, const float* __restrict__ be,
                           float* __restrict__ scale, float* __restrict__ shift, int n,
                           int gOff) {
    int i = blockIdx.x * 256 + threadIdx.x;
    if (i >= n) return;
    float mean = gsum[i] * (1.0f / B_SZ);
    float var  = gsq[i] * (1.0f / B_SZ) - mean * mean;
    float sc   = g[gOff + i] * rsqrtf(var + EPS_BN);
    scale[i] = sc;
    shift[i] = be[gOff + i] - mean * sc;
}

// ---- fused BN2+ReLU+W3 dot+sigmoid+domain select (fp32 out) -------------------
__global__ void k_final(const unsigned short* __restrict__ h2c,
                        const int* __restrict__ domain_id,
                        const float* __restrict__ scale2, const float* __restrict__ shift2,
                        const unsigned short* __restrict__ W3, const unsigned short* __restrict__ b3,
                        float* __restrict__ out, int d0, int nc) {
    int wave = threadIdx.x >> 6, lane = threadIdx.x & 63;
    int b = blockIdx.x * 4 + wave;
    int d = domain_id[b];
    if (d < d0 || d >= d0 + nc) return;
    int o = d * H2 + lane * 8;
    ushort8 v = *(const ushort8*)(h2c + ((long)(d - d0) * B_SZ + b) * H2 + lane * 8);
    ushort8 w = *(const ushort8*)(W3 + o);
    float sum = 0.f;
#pragma unroll
    for (int i = 0; i < 8; i++) {
        float x = b2f(v[i]) * scale2[o + i] + shift2[o + i];
        sum += fmaxf(x, 0.f) * b2f(w[i]);
    }
#pragma unroll
    for (int off = 32; off > 0; off >>= 1) sum += __shfl_xor(sum, off, 64);
    if (lane == 0)
        out[b] = 1.f / (1.f + expf(-(sum + b2f(b3[d]))));
}

__global__ void k_sentinel(float* __restrict__ out, int n) {
    int i = blockIdx.x * 256 + threadIdx.x;
    if (i < n) out[i] = 0.25f;
}

extern "C" void kernel_launch(void* const* d_in, const int* in_sizes, int n_in,
                              void* d_out, int out_size, void* d_ws, size_t ws_size,
                              hipStream_t stream) {
    const int*   feat_ids  = (const int*)d_in[0];
    const int*   domain_id = (const int*)d_in[1];
    const float* tables = (const float*)d_in[2];
    const float* W1  = (const float*)d_in[3];
    const float* g1  = (const float*)d_in[5];
    const float* be1 = (const float*)d_in[6];
    const float* W2  = (const float*)d_in[7];
    const float* g2  = (const float*)d_in[9];
    const float* be2 = (const float*)d_in[10];
    const float* W3  = (const float*)d_in[11];
    const float* b3  = (const float*)d_in[12];

    char* ws = (char*)d_ws;
    float* gsum1  = (float*)ws;            // 8192
    float* gsq1   = gsum1 + 8192;          // 8192
    float* gsum2  = gsq1 + 8192;           // 4096
    float* gsq2   = gsum2 + 4096;          // 4096
    float* scale1 = gsq2 + 4096;           // 8192 (absolute [D][H1])
    float* shift1 = scale1 + 8192;         // 8192
    float* scale2 = shift1 + 8192;         // 4096 (absolute [D][H2])
    float* shift2 = scale2 + 4096;         // 4096
    unsigned short* W1c = (unsigned short*)(ws + (1L  << 20));
    unsigned short* W2c = (unsigned short*)(ws + (9L  << 20));
    unsigned short* W3c = (unsigned short*)(ws + (17L << 20));
    unsigned short* b3c = W3c + D_CNT * H2;
    unsigned short* emb = (unsigned short*)(ws + (18L << 20));

    const long h1Elems = (long)B_SZ * H1;
    const long h2Elems = (long)B_SZ * H2;
    const long perDom  = (h1Elems + h2Elems) * 2;
    const long baseOff = 26L << 20;
    int NC = 0;
    for (int cand = 8; cand >= 1; cand >>= 1)
        if (baseOff + (long)cand * perDom <= (long)ws_size) { NC = cand; break; }
    if (NC == 0) {
        k_sentinel<<<dim3((out_size + 255) / 256), dim3(256), 0, stream>>>(
            (float*)d_out, out_size);
        return;
    }
    unsigned short* h1c = (unsigned short*)(ws + baseOff);
    unsigned short* h2c = h1c + (long)NC * h1Elems;

    k_init<<<dim3(8217), dim3(256), 0, stream>>>(W1, W2, W3, b3, W1c, W2c, W3c, b3c, gsum1);
    k_gather<<<dim3(2048), dim3(256), 0, stream>>>(feat_ids, tables, emb);

    for (int d0 = 0; d0 < D_CNT; d0 += NC) {
        // Layer 1: M=8192,N=1024,K=512 ; 256x256 4-phase pipelined tile
        k_gemm1<<<dim3(32, 4, NC), dim3(512), 0, stream>>>(
            emb, W1c, h1c, gsum1, gsq1, 8192, 1024, 512, 0L, d0);
        k_finalize<<<dim3(NC * 4), dim3(256), 0, stream>>>(
            gsum1 + d0 * H1, gsq1 + d0 * H1, g1, be1,
            scale1 + d0 * H1, shift1 + d0 * H1, NC * H1, d0 * H1);
        // Layer 2: M=8192,N=512,K=1024 ; 128x512 full-N tile, fused BN1+ReLU
        k_gemm2<<<dim3(64, 1, NC), dim3(512), 0, stream>>>(
            h1c, W2c, h2c, gsum2, gsq2, scale1, shift1, 8192, 512, 1024, h1Elems, d0);
        k_finalize<<<dim3(NC * 2), dim3(256), 0, stream>>>(
            gsum2 + d0 * H2, gsq2 + d0 * H2, g2, be2,
            scale2 + d0 * H2, shift2 + d0 * H2, NC * H2, d0 * H2);
        k_final<<<dim3(2048), dim3(256), 0, stream>>>(
            h2c, domain_id, scale2, shift2, W3c, b3c, (float*)d_out, d0, NC);
    }
}